// Round 1
// baseline (2856.443 us; speedup 1.0000x reference)
//
#include <hip/hip_runtime.h>
#include <hip/hip_cooperative_groups.h>
#include <math.h>

namespace cg = cooperative_groups;

#define NN 512
#define ROWS (NN * NN)
#define HH 512

__device__ __forceinline__ float softplus_f(float x) {
    return fmaxf(x, 0.0f) + log1pf(expf(-fabsf(x)));
}

__device__ __forceinline__ float block_sum(float v, float* red4, int tid) {
    #pragma unroll
    for (int s = 1; s < 64; s <<= 1) v += __shfl_xor(v, s);
    if ((tid & 63) == 0) red4[tid >> 6] = v;
    __syncthreads();
    v = red4[0] + red4[1] + red4[2] + red4[3];
    __syncthreads();
    return v;
}

// ---------------------------------------------------------------------------
// Phase 1: fused  h = relu(A@W1+b1);  emb partial;  e = softplus(h@W2+b2)
//          -> outD (diag-masked), outW, embpart[block]
// grid 8192 x 256, tile BM=32 rows x BN=512 (full width) x BK=16
// ---------------------------------------------------------------------------
__global__ __launch_bounds__(256, 2) void fused_mlp(
    const float* __restrict__ A, const float* __restrict__ W1,
    const float* __restrict__ b1, const float* __restrict__ W2,
    const float* __restrict__ b2, float* __restrict__ outD,
    float* __restrict__ outW, float* __restrict__ embpart)
{
    __shared__ float Asub[16][36];     // transposed [k][m], padded
    __shared__ float Bsub[16][512];
    __shared__ float se0[32], se1[32], semb[4];

    const int tid = threadIdx.x;
    const int tn = tid & 63;           // 64 col-groups (one wave = one tm)
    const int tm = tid >> 6;           // 4 row-groups
    const int row0 = blockIdx.x * 32;

    float acc[8][8];
    #pragma unroll
    for (int i = 0; i < 8; i++)
        #pragma unroll
        for (int j = 0; j < 8; j++) acc[i][j] = 0.0f;

    const int lm = tid >> 3;           // A-load row 0..31
    const int lk = (tid & 7) * 2;      // A-load k pair

    for (int k0 = 0; k0 < HH; k0 += 16) {
        float2 av = *reinterpret_cast<const float2*>(
            &A[(size_t)(row0 + lm) * HH + k0 + lk]);
        const float4* W1v = reinterpret_cast<const float4*>(W1) + (size_t)k0 * 128;
        float4 bvv[8];
        #pragma unroll
        for (int i = 0; i < 8; i++) bvv[i] = W1v[tid + i * 256];

        Asub[lk][lm] = av.x;
        Asub[lk + 1][lm] = av.y;
        #pragma unroll
        for (int i = 0; i < 8; i++) {
            int f4 = tid + i * 256;
            int kk = f4 >> 7, c4 = f4 & 127;
            *reinterpret_cast<float4*>(&Bsub[kk][c4 * 4]) = bvv[i];
        }
        __syncthreads();
        #pragma unroll
        for (int kk = 0; kk < 16; kk++) {
            float a[8], b[8];
            *reinterpret_cast<float4*>(&a[0]) = *reinterpret_cast<const float4*>(&Asub[kk][tm * 8]);
            *reinterpret_cast<float4*>(&a[4]) = *reinterpret_cast<const float4*>(&Asub[kk][tm * 8 + 4]);
            *reinterpret_cast<float4*>(&b[0]) = *reinterpret_cast<const float4*>(&Bsub[kk][tn * 8]);
            *reinterpret_cast<float4*>(&b[4]) = *reinterpret_cast<const float4*>(&Bsub[kk][tn * 8 + 4]);
            #pragma unroll
            for (int i = 0; i < 8; i++)
                #pragma unroll
                for (int j = 0; j < 8; j++)
                    acc[i][j] = fmaf(a[i], b[j], acc[i][j]);
        }
        __syncthreads();
    }

    // epilogue: bias + relu + dots with W2 + emb partial
    float p0[8], p1[8];
    #pragma unroll
    for (int i = 0; i < 8; i++) { p0[i] = 0.0f; p1[i] = 0.0f; }
    float embt = 0.0f;
    #pragma unroll
    for (int j = 0; j < 8; j++) {
        int col = tn * 8 + j;
        float bb = b1[col];
        float w20 = W2[col * 2 + 0];
        float w21 = W2[col * 2 + 1];
        #pragma unroll
        for (int i = 0; i < 8; i++) {
            float h = fmaxf(acc[i][j] + bb, 0.0f);
            p0[i] = fmaf(h, w20, p0[i]);
            p1[i] = fmaf(h, w21, p1[i]);
            embt += h;
        }
    }
    #pragma unroll
    for (int i = 0; i < 8; i++) {
        float v0 = p0[i], v1 = p1[i];
        #pragma unroll
        for (int s = 1; s < 64; s <<= 1) { v0 += __shfl_xor(v0, s); v1 += __shfl_xor(v1, s); }
        if (tn == 0) { se0[tm * 8 + i] = v0; se1[tm * 8 + i] = v1; }
    }
    #pragma unroll
    for (int s = 1; s < 64; s <<= 1) embt += __shfl_xor(embt, s);
    if (tn == 0) semb[tm] = embt;
    __syncthreads();
    if (tid < 32) {
        int gr = row0 + tid;
        float e0 = se0[tid] + b2[0];
        float e1 = se1[tid] + b2[1];
        int di = gr >> 9, dj = gr & 511;
        outD[gr] = (di == dj) ? 0.0f : softplus_f(e0);
        outW[gr] = softplus_f(e1);
    }
    if (tid == 0) embpart[blockIdx.x] = semb[0] + semb[1] + semb[2] + semb[3];
}

// ---------------------------------------------------------------------------
// Phases 2-4 in one cooperative kernel: 32 blocks x 256 threads, 16 rows/block
// ---------------------------------------------------------------------------
__global__ __launch_bounds__(256, 1) void coop_post(
    const float* __restrict__ Dg, const float* __restrict__ Wg,
    const float* __restrict__ noise, const float* __restrict__ uinit,
    float* __restrict__ outE, float* __restrict__ outX,
    float* __restrict__ ws)
{
    cg::grid_group grid = cg::this_grid();
    __shared__ float Dl[16][516];      // D rows (pad vs bank conflicts)
    __shared__ float S1[16][520];      // W + W^T rows
    __shared__ float S2[16][520];      // W.D + (W.D)^T rows
    __shared__ float Xl[512][4];
    __shared__ float ul[512];
    __shared__ float upl[3][512];
    __shared__ float rm[16];
    __shared__ float red4[4];

    const int tid = threadIdx.x;
    const int bid = blockIdx.x;
    const int r0 = bid * 16;

    float* embpart = ws;                    // [8192]
    float* colpart = ws + 8192;             // [32*512]
    float* colmean = colpart + 32 * 512;    // [512]
    float* ubuf0   = colmean + 512;         // [512]
    float* ubuf1   = ubuf0 + 512;           // [512]
    float* Xg0     = ubuf1 + 512;           // [2048]
    float* Xg1     = Xg0 + 2048;            // [2048]

    // ---- phase 2a: load D rows, row means, column partial sums
    for (int idx = tid; idx < 16 * 512; idx += 256) {
        int r = idx >> 9, c = idx & 511;
        Dl[r][c] = Dg[(size_t)(r0 + r) * NN + c];
    }
    __syncthreads();
    {
        int r = tid >> 4, l = tid & 15;
        float s = 0.0f;
        for (int j = l; j < 512; j += 16) s += Dl[r][j];
        #pragma unroll
        for (int st = 1; st < 16; st <<= 1) s += __shfl_xor(s, st);
        if (l == 0) rm[r] = s * (1.0f / 512.0f);
    }
    for (int c = tid; c < 512; c += 256) {
        float s = 0.0f;
        #pragma unroll
        for (int r = 0; r < 16; r++) s += Dl[r][c];
        colpart[bid * 512 + c] = s;
    }
    grid.sync();

    // ---- phase 2b: column means (own 16 cols); emb total (block 0)
    {
        int cl = tid >> 4;
        int pp = tid & 15;
        int col = bid * 16 + cl;
        float s = colpart[(2 * pp) * 512 + col] + colpart[(2 * pp + 1) * 512 + col];
        #pragma unroll
        for (int st = 1; st < 16; st <<= 1) s += __shfl_xor(s, st);
        if (pp == 0) colmean[col] = s * (1.0f / 512.0f);
    }
    if (bid == 0) {
        float s = 0.0f;
        for (int i = tid; i < 8192; i += 256) s += embpart[i];
        s = block_sum(s, red4, tid);
        if (tid == 0) outE[0] = s;
    }
    grid.sync();

    // ---- phase 2c: Dmean (redundant per block)
    float Dmean;
    {
        float s = colmean[tid] + colmean[tid + 256];
        s = block_sum(s, red4, tid);
        Dmean = s * (1.0f / 512.0f);
    }

    // ---- phase 3: power iteration with implicit deflation
    const int mr = tid >> 4;
    const int ml = tid & 15;
    int cur = 0;
    #pragma unroll 1
    for (int rank = 0; rank < 3; rank++) {
        #pragma unroll 1
        for (int step = 0; step < 10; step++) {
            if (step == 0) {
                for (int t = tid; t < 512; t += 256) ul[t] = uinit[t * 3 + rank];
            } else {
                const float* ub = cur ? ubuf1 : ubuf0;
                for (int t = tid; t < 512; t += 256) ul[t] = ub[t];
            }
            __syncthreads();
            float vn = 0, vs = 0, vdr = 0, vd0 = 0, vd1 = 0;
            for (int t = tid; t < 512; t += 256) {
                float u = ul[t];
                vn = fmaf(u, u, vn);
                vs += u;
                vdr = fmaf(colmean[t], u, vdr);
                if (rank > 0) vd0 = fmaf(upl[0][t], u, vd0);
                if (rank > 1) vd1 = fmaf(upl[1][t], u, vd1);
            }
            float nrm2 = block_sum(vn, red4, tid);
            float Su   = block_sum(vs, red4, tid);
            float dru  = block_sum(vdr, red4, tid);
            float d0u = 0, d1u = 0;
            if (rank > 0) d0u = block_sum(vd0, red4, tid);
            if (rank > 1) d1u = block_sum(vd1, red4, tid);
            float inv = 1.0f / fmaxf(sqrtf(nrm2), 0.001f);
            float S = Su * inv, dr = dru * inv;
            float d0s = d0u * inv, d1s = d1u * inv;
            float a = 0.0f;
            for (int j = ml; j < 512; j += 16) a = fmaf(Dl[mr][j], ul[j], a);
            #pragma unroll
            for (int st = 1; st < 16; st <<= 1) a += __shfl_xor(a, st);
            if (ml == 0) {
                float bvv = -0.5f * (a * inv - dr - rm[mr] * S + Dmean * S);
                if (rank > 0) bvv -= d0s * upl[0][r0 + mr];
                if (rank > 1) bvv -= d1s * upl[1][r0 + mr];
                float* ubn = cur ? ubuf0 : ubuf1;
                ubn[r0 + mr] = bvv;
            }
            grid.sync();
            cur ^= 1;
        }
        // finalize rank
        {
            const float* ub = cur ? ubuf1 : ubuf0;
            for (int t = tid; t < 512; t += 256) ul[t] = ub[t];
        }
        __syncthreads();
        float vn = 0.0f;
        for (int t = tid; t < 512; t += 256) { float u = ul[t]; vn = fmaf(u, u, vn); }
        float eig2 = block_sum(vn, red4, tid);
        float scl = sqrtf(sqrtf(eig2 + 0.01f));
        for (int t = tid; t < 512; t += 256) upl[rank][t] = ul[t] * scl;
        if (tid < 16) {
            int gr = r0 + tid;
            Xg0[gr * 4 + rank] = fmaf(ul[gr], scl, noise[gr * 3 + rank]);
            if (rank == 0) Xg0[gr * 4 + 3] = 0.0f;
        }
        __syncthreads();
    }

    // ---- phase 4 prep: SW = W+W^T, SWD = W.D + (W.D)^T (own rows)
    for (int idx = tid; idx < 16 * 512; idx += 256) {
        int r = idx >> 9, j = idx & 511;
        int gr = r0 + r;
        float wr = Wg[(size_t)gr * NN + j];
        float wc = Wg[(size_t)j * NN + gr];
        float dc = Dg[(size_t)j * NN + gr];
        S1[r][j] = wr + wc;
        S2[r][j] = fmaf(wr, Dl[r][j], wc * dc);
    }
    grid.sync();

    // ---- phase 4: 100 gradient-flow steps
    const int gr4 = (r0 + mr) * 4;
    int par = 0;
    #pragma unroll 1
    for (int t = 0; t < 100; t++) {
        const float* Xs = par ? Xg1 : Xg0;
        float* Xd = par ? Xg0 : Xg1;
        for (int i = tid; i < 512; i += 256)
            *reinterpret_cast<float4*>(&Xl[i][0]) =
                *reinterpret_cast<const float4*>(&Xs[i * 4]);
        __syncthreads();
        float xr0 = Xl[r0 + mr][0], xr1 = Xl[r0 + mr][1], xr2 = Xl[r0 + mr][2];
        float g0 = 0, g1 = 0, g2 = 0;
        for (int j = ml; j < 512; j += 16) {
            float dx0 = xr0 - Xl[j][0];
            float dx1 = xr1 - Xl[j][1];
            float dx2 = xr2 - Xl[j][2];
            float d2 = fmaf(dx0, dx0, fmaf(dx1, dx1, fmaf(dx2, dx2, 0.01f)));
            float ri = rsqrtf(d2);
            float coef = fmaf(S2[mr][j], ri, -S1[mr][j]);
            g0 = fmaf(coef, dx0, g0);
            g1 = fmaf(coef, dx1, g1);
            g2 = fmaf(coef, dx2, g2);
        }
        #pragma unroll
        for (int st = 1; st < 16; st <<= 1) {
            g0 += __shfl_xor(g0, st);
            g1 += __shfl_xor(g1, st);
            g2 += __shfl_xor(g2, st);
        }
        if (ml == 0) {
            float dX0 = 0.2f * g0, dX1 = 0.2f * g1, dX2 = 0.2f * g2;
            float sp = sqrtf(fmaf(dX0, dX0, fmaf(dX1, dX1, fmaf(dX2, dX2, 0.001f))));
            float alpha = 0.1f + 4.9f * (float)(100 - t) * 0.01f;
            float scal = alpha * tanhf(sp / alpha) / sp;
            Xd[gr4 + 0] = fmaf(dX0, scal, xr0);
            Xd[gr4 + 1] = fmaf(dX1, scal, xr1);
            Xd[gr4 + 2] = fmaf(dX2, scal, xr2);
        }
        grid.sync();
        par ^= 1;
    }
    if (tid < 16) {
        int gr = r0 + tid;
        const float* Xs = par ? Xg1 : Xg0;
        outX[gr * 3 + 0] = Xs[gr * 4 + 0];
        outX[gr * 3 + 1] = Xs[gr * 4 + 1];
        outX[gr * 3 + 2] = Xs[gr * 4 + 2];
    }
}

extern "C" void kernel_launch(void* const* d_in, const int* in_sizes, int n_in,
                              void* d_out, int out_size, void* d_ws, size_t ws_size,
                              hipStream_t stream)
{
    const float* A     = (const float*)d_in[0];
    const float* W1    = (const float*)d_in[1];
    const float* b1    = (const float*)d_in[2];
    const float* W2    = (const float*)d_in[3];
    const float* b2    = (const float*)d_in[4];
    const float* noise = (const float*)d_in[5];
    const float* uinit = (const float*)d_in[6];

    float* out  = (float*)d_out;
    float* outD = out;
    float* outW = out + ROWS;
    float* outE = out + 2 * ROWS;
    float* outX = out + 2 * ROWS + 1;
    float* ws   = (float*)d_ws;

    hipLaunchKernelGGL(fused_mlp, dim3(ROWS / 32), dim3(256), 0, stream,
                       A, W1, b1, W2, b2, outD, outW, ws);

    const float* Dg  = outD;
    const float* Wgc = outW;
    void* args[] = { (void*)&Dg, (void*)&Wgc, (void*)&noise, (void*)&uinit,
                     (void*)&outE, (void*)&outX, (void*)&ws };
    hipLaunchCooperativeKernel((const void*)coop_post, dim3(32), dim3(256),
                               args, 0, stream);
}

// Round 2
// 1233.405 us; speedup vs baseline: 2.3159x; 2.3159x over previous
//
#include <hip/hip_runtime.h>
#include <hip/hip_bf16.h>
#include <math.h>

#define NN 512
#define ROWS (NN * NN)
#define HH 512

// ws layout (float offsets)
#define WS_EMB   0                       // [2048] emb partials (one per fused_mlp block)
#define WS_COLP  2048                    // [32*512] column partial sums
#define WS_COLM  (WS_COLP + 32*512)      // [512] column means
#define WS_U0    (WS_COLM + 512)         // [512]
#define WS_U1    (WS_U0 + 512)           // [512]
#define WS_X0    (WS_U1 + 512)           // [2048]
#define WS_X1    (WS_X0 + 2048)          // [2048]
#define WS_W1T   (WS_X1 + 2048)          // [131072] = 262144 bf16 (W1 transposed)
#define WS_BAR   (WS_W1T + 131072)       // [64] ints: arrive[32], gen at +32

typedef __attribute__((ext_vector_type(8))) short bf16x8;
typedef __attribute__((ext_vector_type(4))) float f32x4;

__device__ __forceinline__ short f2bf(float f) {
    union { float f; unsigned u; } v; v.f = f;
    unsigned r = v.u + 0x7fffu + ((v.u >> 16) & 1u);
    return (short)(r >> 16);
}

__device__ __forceinline__ float softplus_f(float x) {
    return fmaxf(x, 0.0f) + log1pf(expf(-fabsf(x)));
}

__device__ __forceinline__ float block_sum(float v, float* red4, int tid) {
    #pragma unroll
    for (int s = 1; s < 64; s <<= 1) v += __shfl_xor(v, s);
    if ((tid & 63) == 0) red4[tid >> 6] = v;
    __syncthreads();
    v = red4[0] + red4[1] + red4[2] + red4[3];
    __syncthreads();
    return v;
}

// ---------------------------------------------------------------------------
// W1 (fp32 [k][n]) -> W1T (bf16 [n][k]) transpose+convert
// ---------------------------------------------------------------------------
__global__ void w1t_prep(const float* __restrict__ W1, short* __restrict__ W1T)
{
    __shared__ float tile[32][33];
    const int bx = blockIdx.x & 15;        // n tile
    const int by = blockIdx.x >> 4;        // k tile
    const int tx = threadIdx.x & 31;
    const int ty = threadIdx.x >> 5;       // 0..7
    const int n0 = bx * 32, k0 = by * 32;
    #pragma unroll
    for (int i = 0; i < 4; i++)
        tile[ty + i * 8][tx] = W1[(size_t)(k0 + ty + i * 8) * HH + n0 + tx];
    __syncthreads();
    #pragma unroll
    for (int i = 0; i < 4; i++)
        W1T[(size_t)(n0 + ty + i * 8) * HH + k0 + tx] = f2bf(tile[tx][ty + i * 8]);
}

// ---------------------------------------------------------------------------
// Phase 1: h = relu(A@W1+b1) via bf16 MFMA; fused epilogue -> D, W, emb parts
// 2048 blocks x 512 thr; BM=128, BN=512 (full), BK=32; 8 waves x (128r x 64c)
// A staged fp32->bf16 through LDS (padded); B frags read direct from L2 (W1T)
// ---------------------------------------------------------------------------
__global__ __launch_bounds__(512, 2) void fused_mlp(
    const float* __restrict__ A, const short* __restrict__ W1T,
    const float* __restrict__ b1, const float* __restrict__ W2,
    const float* __restrict__ b2, float* __restrict__ outD,
    float* __restrict__ outW, float* __restrict__ embpart)
{
    __shared__ short As[2][128 * 40];      // pad 32->40 elems per row
    __shared__ float sp0[8][128], sp1[8][128];
    __shared__ float semb[8];

    const int tid = threadIdx.x;
    const int lane = tid & 63;
    const int wc = tid >> 6;               // wave id = column group 0..7
    const int l15 = lane & 15;
    const int l4 = lane >> 4;
    const int row0 = blockIdx.x * 128;

    f32x4 acc[8][4];
    #pragma unroll
    for (int m = 0; m < 8; m++)
        #pragma unroll
        for (int n = 0; n < 4; n++) {
            f32x4 z = {0.0f, 0.0f, 0.0f, 0.0f};
            acc[m][n] = z;
        }

    // A staging: thread -> row sr, k-chunk skc (8 consecutive k)
    const int sr = tid >> 2;               // 0..127
    const int skc = (tid & 3) * 8;         // 0,8,16,24
    const float* agp = A + (size_t)(row0 + sr) * HH + skc;

    // prologue: stage k0=0 into buf 0
    {
        float4 a0 = *(const float4*)(agp);
        float4 a1 = *(const float4*)(agp + 4);
        bf16x8 w;
        w[0] = f2bf(a0.x); w[1] = f2bf(a0.y); w[2] = f2bf(a0.z); w[3] = f2bf(a0.w);
        w[4] = f2bf(a1.x); w[5] = f2bf(a1.y); w[6] = f2bf(a1.z); w[7] = f2bf(a1.w);
        *(bf16x8*)&As[0][sr * 40 + skc] = w;
    }
    __syncthreads();

    int cur = 0;
    #pragma unroll 1
    for (int s = 0; s < 16; s++) {
        const int k0 = s * 32;
        // B fragments direct from global (L2-resident W1T)
        bf16x8 bfr[4];
        #pragma unroll
        for (int n = 0; n < 4; n++) {
            int col = wc * 64 + n * 16 + l15;
            bfr[n] = *(const bf16x8*)(W1T + (size_t)col * HH + k0 + l4 * 8);
        }
        // prefetch next A tile into regs
        float4 p0v, p1v;
        if (s < 15) {
            p0v = *(const float4*)(agp + k0 + 32);
            p1v = *(const float4*)(agp + k0 + 36);
        }
        // A fragments from LDS
        bf16x8 af[8];
        #pragma unroll
        for (int m = 0; m < 8; m++)
            af[m] = *(const bf16x8*)&As[cur][(m * 16 + l15) * 40 + l4 * 8];
        #pragma unroll
        for (int m = 0; m < 8; m++)
            #pragma unroll
            for (int n = 0; n < 4; n++)
                acc[m][n] = __builtin_amdgcn_mfma_f32_16x16x32_bf16(
                    af[m], bfr[n], acc[m][n], 0, 0, 0);
        if (s < 15) {
            bf16x8 w;
            w[0] = f2bf(p0v.x); w[1] = f2bf(p0v.y); w[2] = f2bf(p0v.z); w[3] = f2bf(p0v.w);
            w[4] = f2bf(p1v.x); w[5] = f2bf(p1v.y); w[6] = f2bf(p1v.z); w[7] = f2bf(p1v.w);
            *(bf16x8*)&As[cur ^ 1][sr * 40 + skc] = w;
        }
        __syncthreads();
        cur ^= 1;
    }

    // epilogue: bias+relu, dot with W2 cols, emb partial
    float b1c[4], w20[4], w21[4];
    #pragma unroll
    for (int n = 0; n < 4; n++) {
        int col = wc * 64 + n * 16 + l15;
        b1c[n] = b1[col];
        w20[n] = W2[col * 2 + 0];
        w21[n] = W2[col * 2 + 1];
    }
    float embl = 0.0f;
    #pragma unroll
    for (int m = 0; m < 8; m++) {
        #pragma unroll
        for (int j = 0; j < 4; j++) {
            float s0 = 0.0f, s1 = 0.0f;
            #pragma unroll
            for (int n = 0; n < 4; n++) {
                float h = fmaxf(acc[m][n][j] + b1c[n], 0.0f);
                s0 = fmaf(h, w20[n], s0);
                s1 = fmaf(h, w21[n], s1);
                embl += h;
            }
            #pragma unroll
            for (int st = 1; st < 16; st <<= 1) {
                s0 += __shfl_xor(s0, st);
                s1 += __shfl_xor(s1, st);
            }
            if (l15 == 0) {
                int row = m * 16 + l4 * 4 + j;
                sp0[wc][row] = s0;
                sp1[wc][row] = s1;
            }
        }
    }
    #pragma unroll
    for (int st = 1; st < 64; st <<= 1) embl += __shfl_xor(embl, st);
    if (lane == 0) semb[wc] = embl;
    __syncthreads();
    if (tid < 128) {
        int gr = row0 + tid;
        float p0 = b2[0], p1 = b2[1];
        #pragma unroll
        for (int w = 0; w < 8; w++) { p0 += sp0[w][tid]; p1 += sp1[w][tid]; }
        int di = gr >> 9, dj = gr & 511;
        outD[gr] = (di == dj) ? 0.0f : softplus_f(p0);
        outW[gr] = softplus_f(p1);
    }
    if (tid == 0) {
        float e = 0.0f;
        #pragma unroll
        for (int w = 0; w < 8; w++) e += semb[w];
        embpart[blockIdx.x] = e;
    }
}

// ---------------------------------------------------------------------------
// lightweight grid barrier: flag-array + generation broadcast (agent scope)
// ---------------------------------------------------------------------------
__device__ __forceinline__ void gbar(int* arrive, int* gen, int g)
{
    const int tid = threadIdx.x;
    const int bid = blockIdx.x;
    __syncthreads();
    if (bid == 0) {
        if (tid >= 1 && tid < 32) {
            while (__hip_atomic_load(&arrive[tid], __ATOMIC_ACQUIRE,
                                     __HIP_MEMORY_SCOPE_AGENT) < g)
                __builtin_amdgcn_s_sleep(1);
        }
        __syncthreads();
        if (tid == 0)
            __hip_atomic_store(gen, g, __ATOMIC_RELEASE, __HIP_MEMORY_SCOPE_AGENT);
    } else {
        if (tid == 0) {
            __hip_atomic_store(&arrive[bid], g, __ATOMIC_RELEASE,
                               __HIP_MEMORY_SCOPE_AGENT);
            while (__hip_atomic_load(gen, __ATOMIC_ACQUIRE,
                                     __HIP_MEMORY_SCOPE_AGENT) < g)
                __builtin_amdgcn_s_sleep(1);
        }
        __syncthreads();
    }
}

// ---------------------------------------------------------------------------
// Phases 2-4: 32 blocks x 256 threads, 16 rows/block
// ---------------------------------------------------------------------------
__global__ __launch_bounds__(256, 1) void coop_post(
    const float* __restrict__ Dg, const float* __restrict__ Wg,
    const float* __restrict__ noise, const float* __restrict__ uinit,
    float* __restrict__ outE, float* __restrict__ outX,
    float* __restrict__ ws)
{
    __shared__ float Dl[16][516];
    __shared__ float S1[16][520];
    __shared__ float S2[16][520];
    __shared__ float Xl[512][4];
    __shared__ float ul[512];
    __shared__ float upl[3][512];
    __shared__ float rm[16];
    __shared__ float red4[4];

    const int tid = threadIdx.x;
    const int bid = blockIdx.x;
    const int r0 = bid * 16;

    float* embpart = ws + WS_EMB;
    float* colpart = ws + WS_COLP;
    float* colmean = ws + WS_COLM;
    float* ubuf0   = ws + WS_U0;
    float* ubuf1   = ws + WS_U1;
    float* Xg0     = ws + WS_X0;
    float* Xg1     = ws + WS_X1;
    int* arrive    = (int*)(ws + WS_BAR);
    int* gen       = arrive + 32;
    int bg = 0;

    // ---- phase 2a: load D rows, row means, column partial sums
    for (int idx = tid; idx < 16 * 512; idx += 256) {
        int r = idx >> 9, c = idx & 511;
        Dl[r][c] = Dg[(size_t)(r0 + r) * NN + c];
    }
    __syncthreads();
    {
        int r = tid >> 4, l = tid & 15;
        float s = 0.0f;
        for (int j = l; j < 512; j += 16) s += Dl[r][j];
        #pragma unroll
        for (int st = 1; st < 16; st <<= 1) s += __shfl_xor(s, st);
        if (l == 0) rm[r] = s * (1.0f / 512.0f);
    }
    for (int c = tid; c < 512; c += 256) {
        float s = 0.0f;
        #pragma unroll
        for (int r = 0; r < 16; r++) s += Dl[r][c];
        colpart[bid * 512 + c] = s;
    }
    gbar(arrive, gen, ++bg);

    // ---- phase 2b: column means; emb total (block 0)
    {
        int cl = tid >> 4;
        int pp = tid & 15;
        int col = bid * 16 + cl;
        float s = colpart[(2 * pp) * 512 + col] + colpart[(2 * pp + 1) * 512 + col];
        #pragma unroll
        for (int st = 1; st < 16; st <<= 1) s += __shfl_xor(s, st);
        if (pp == 0) colmean[col] = s * (1.0f / 512.0f);
    }
    if (bid == 0) {
        float s = 0.0f;
        for (int i = tid; i < ROWS / 128; i += 256) s += embpart[i];
        s = block_sum(s, red4, tid);
        if (tid == 0) outE[0] = s;
    }
    gbar(arrive, gen, ++bg);

    // ---- phase 2c: Dmean (redundant per block)
    float Dmean;
    {
        float s = colmean[tid] + colmean[tid + 256];
        s = block_sum(s, red4, tid);
        Dmean = s * (1.0f / 512.0f);
    }

    // ---- phase 3: power iteration with implicit deflation
    const int mr = tid >> 4;
    const int ml = tid & 15;
    int cur = 0;
    #pragma unroll 1
    for (int rank = 0; rank < 3; rank++) {
        #pragma unroll 1
        for (int step = 0; step < 10; step++) {
            if (step == 0) {
                for (int t = tid; t < 512; t += 256) ul[t] = uinit[t * 3 + rank];
            } else {
                const float* ub = cur ? ubuf1 : ubuf0;
                for (int t = tid; t < 512; t += 256) ul[t] = ub[t];
            }
            __syncthreads();
            float vn = 0, vs = 0, vdr = 0, vd0 = 0, vd1 = 0;
            for (int t = tid; t < 512; t += 256) {
                float u = ul[t];
                vn = fmaf(u, u, vn);
                vs += u;
                vdr = fmaf(colmean[t], u, vdr);
                if (rank > 0) vd0 = fmaf(upl[0][t], u, vd0);
                if (rank > 1) vd1 = fmaf(upl[1][t], u, vd1);
            }
            float nrm2 = block_sum(vn, red4, tid);
            float Su   = block_sum(vs, red4, tid);
            float dru  = block_sum(vdr, red4, tid);
            float d0u = 0, d1u = 0;
            if (rank > 0) d0u = block_sum(vd0, red4, tid);
            if (rank > 1) d1u = block_sum(vd1, red4, tid);
            float inv = 1.0f / fmaxf(sqrtf(nrm2), 0.001f);
            float S = Su * inv, dr = dru * inv;
            float d0s = d0u * inv, d1s = d1u * inv;
            float a = 0.0f;
            for (int j = ml; j < 512; j += 16) a = fmaf(Dl[mr][j], ul[j], a);
            #pragma unroll
            for (int st = 1; st < 16; st <<= 1) a += __shfl_xor(a, st);
            if (ml == 0) {
                float bvv = -0.5f * (a * inv - dr - rm[mr] * S + Dmean * S);
                if (rank > 0) bvv -= d0s * upl[0][r0 + mr];
                if (rank > 1) bvv -= d1s * upl[1][r0 + mr];
                float* ubn = cur ? ubuf0 : ubuf1;
                ubn[r0 + mr] = bvv;
            }
            gbar(arrive, gen, ++bg);
            cur ^= 1;
        }
        // finalize rank
        {
            const float* ub = cur ? ubuf1 : ubuf0;
            for (int t = tid; t < 512; t += 256) ul[t] = ub[t];
        }
        __syncthreads();
        float vn = 0.0f;
        for (int t = tid; t < 512; t += 256) { float u = ul[t]; vn = fmaf(u, u, vn); }
        float eig2 = block_sum(vn, red4, tid);
        float scl = sqrtf(sqrtf(eig2 + 0.01f));
        for (int t = tid; t < 512; t += 256) upl[rank][t] = ul[t] * scl;
        if (tid < 16) {
            int gr = r0 + tid;
            Xg0[gr * 4 + rank] = fmaf(ul[gr], scl, noise[gr * 3 + rank]);
            if (rank == 0) Xg0[gr * 4 + 3] = 0.0f;
        }
        __syncthreads();
    }

    // ---- phase 4 prep: SW = W+W^T, SWD = W.D + (W.D)^T (own rows)
    for (int idx = tid; idx < 16 * 512; idx += 256) {
        int r = idx >> 9, j = idx & 511;
        int gr = r0 + r;
        float wr = Wg[(size_t)gr * NN + j];
        float wc = Wg[(size_t)j * NN + gr];
        float dc = Dg[(size_t)j * NN + gr];
        S1[r][j] = wr + wc;
        S2[r][j] = fmaf(wr, Dl[r][j], wc * dc);
    }
    gbar(arrive, gen, ++bg);

    // ---- phase 4: 100 gradient-flow steps
    const int gr4 = (r0 + mr) * 4;
    int par = 0;
    #pragma unroll 1
    for (int t = 0; t < 100; t++) {
        const float* Xs = par ? Xg1 : Xg0;
        float* Xd = par ? Xg0 : Xg1;
        for (int i = tid; i < 512; i += 256)
            *reinterpret_cast<float4*>(&Xl[i][0]) =
                *reinterpret_cast<const float4*>(&Xs[i * 4]);
        __syncthreads();
        float xr0 = Xl[r0 + mr][0], xr1 = Xl[r0 + mr][1], xr2 = Xl[r0 + mr][2];
        float g0 = 0, g1 = 0, g2 = 0;
        for (int j = ml; j < 512; j += 16) {
            float dx0 = xr0 - Xl[j][0];
            float dx1 = xr1 - Xl[j][1];
            float dx2 = xr2 - Xl[j][2];
            float d2 = fmaf(dx0, dx0, fmaf(dx1, dx1, fmaf(dx2, dx2, 0.01f)));
            float ri = rsqrtf(d2);
            float coef = fmaf(S2[mr][j], ri, -S1[mr][j]);
            g0 = fmaf(coef, dx0, g0);
            g1 = fmaf(coef, dx1, g1);
            g2 = fmaf(coef, dx2, g2);
        }
        #pragma unroll
        for (int st = 1; st < 16; st <<= 1) {
            g0 += __shfl_xor(g0, st);
            g1 += __shfl_xor(g1, st);
            g2 += __shfl_xor(g2, st);
        }
        if (ml == 0) {
            float dX0 = 0.2f * g0, dX1 = 0.2f * g1, dX2 = 0.2f * g2;
            float sp = sqrtf(fmaf(dX0, dX0, fmaf(dX1, dX1, fmaf(dX2, dX2, 0.001f))));
            float alpha = 0.1f + 4.9f * (float)(100 - t) * 0.01f;
            float scal = alpha * tanhf(sp / alpha) / sp;
            Xd[gr4 + 0] = fmaf(dX0, scal, xr0);
            Xd[gr4 + 1] = fmaf(dX1, scal, xr1);
            Xd[gr4 + 2] = fmaf(dX2, scal, xr2);
        }
        gbar(arrive, gen, ++bg);
        par ^= 1;
    }
    if (tid < 16) {
        int gr = r0 + tid;
        const float* Xs = par ? Xg1 : Xg0;
        outX[gr * 3 + 0] = Xs[gr * 4 + 0];
        outX[gr * 3 + 1] = Xs[gr * 4 + 1];
        outX[gr * 3 + 2] = Xs[gr * 4 + 2];
    }
}

extern "C" void kernel_launch(void* const* d_in, const int* in_sizes, int n_in,
                              void* d_out, int out_size, void* d_ws, size_t ws_size,
                              hipStream_t stream)
{
    const float* A     = (const float*)d_in[0];
    const float* W1    = (const float*)d_in[1];
    const float* b1    = (const float*)d_in[2];
    const float* W2    = (const float*)d_in[3];
    const float* b2    = (const float*)d_in[4];
    const float* noise = (const float*)d_in[5];
    const float* uinit = (const float*)d_in[6];

    float* out  = (float*)d_out;
    float* outD = out;
    float* outW = out + ROWS;
    float* outE = out + 2 * ROWS;
    float* outX = out + 2 * ROWS + 1;
    float* ws   = (float*)d_ws;
    short* W1T  = (short*)(ws + WS_W1T);

    // reset barrier state every call (harness does not re-poison between replays)
    hipMemsetAsync((char*)d_ws + (size_t)WS_BAR * sizeof(float), 0, 256, stream);

    hipLaunchKernelGGL(w1t_prep, dim3(256), dim3(256), 0, stream, W1, W1T);

    hipLaunchKernelGGL(fused_mlp, dim3(ROWS / 128), dim3(512), 0, stream,
                       A, W1T, b1, W2, b2, outD, outW, ws + WS_EMB);

    const float* Dg  = outD;
    const float* Wgc = outW;
    void* args[] = { (void*)&Dg, (void*)&Wgc, (void*)&noise, (void*)&uinit,
                     (void*)&outE, (void*)&outX, (void*)&ws };
    hipLaunchCooperativeKernel((const void*)coop_post, dim3(32), dim3(256),
                               args, 0, stream);
}

// Round 3
// 1142.645 us; speedup vs baseline: 2.4999x; 1.0794x over previous
//
#include <hip/hip_runtime.h>
#include <hip/hip_bf16.h>
#include <math.h>

#define NN 512
#define ROWS (NN * NN)
#define HH 512

// ws layout (float offsets)
#define WS_EMB   0                       // [4096] emb partials (one per fused_mlp block)
#define WS_COLP  4096                    // [32*512] column partial sums
#define WS_U0    (WS_COLP + 32*512)      // [512]
#define WS_U1    (WS_U0 + 512)           // [512]
#define WS_X0    (WS_U1 + 512)           // [2048]
#define WS_X1    (WS_X0 + 2048)          // [2048]
#define WS_W1T   (WS_X1 + 2048)          // [131072] = 262144 bf16 (W1 transposed)
#define WS_BAR   (WS_W1T + 131072)       // [512] ints: 32 flags x 16-int stride (64B)

typedef __attribute__((ext_vector_type(8))) short bf16x8;
typedef __attribute__((ext_vector_type(4))) float f32x4;

__device__ __forceinline__ short f2bf(float f) {   // RTNE (used in prep only)
    union { float f; unsigned u; } v; v.f = f;
    unsigned r = v.u + 0x7fffu + ((v.u >> 16) & 1u);
    return (short)(r >> 16);
}

// pack two fp32 -> two bf16 (truncation) in one v_perm_b32
__device__ __forceinline__ unsigned pack_bf2(float lo, float hi) {
    return __builtin_amdgcn_perm(__float_as_uint(hi), __float_as_uint(lo),
                                 0x07060302u);
}

__device__ __forceinline__ float softplus_f(float x) {
    return fmaxf(x, 0.0f) + log1pf(expf(-fabsf(x)));
}

__device__ __forceinline__ float block_sum(float v, float* red4, int tid) {
    #pragma unroll
    for (int s = 1; s < 64; s <<= 1) v += __shfl_xor(v, s);
    if ((tid & 63) == 0) red4[tid >> 6] = v;
    __syncthreads();
    v = red4[0] + red4[1] + red4[2] + red4[3];
    __syncthreads();
    return v;
}

// ---------------------------------------------------------------------------
// W1 (fp32 [k][n]) -> W1T (bf16 [n][k]) transpose+convert
// ---------------------------------------------------------------------------
__global__ void w1t_prep(const float* __restrict__ W1, short* __restrict__ W1T)
{
    __shared__ float tile[32][33];
    const int bx = blockIdx.x & 15;        // n tile
    const int by = blockIdx.x >> 4;        // k tile
    const int tx = threadIdx.x & 31;
    const int ty = threadIdx.x >> 5;       // 0..7
    const int n0 = bx * 32, k0 = by * 32;
    #pragma unroll
    for (int i = 0; i < 4; i++)
        tile[ty + i * 8][tx] = W1[(size_t)(k0 + ty + i * 8) * HH + n0 + tx];
    __syncthreads();
    #pragma unroll
    for (int i = 0; i < 4; i++)
        W1T[(size_t)(n0 + ty + i * 8) * HH + k0 + tx] = f2bf(tile[tx][ty + i * 8]);
}

// ---------------------------------------------------------------------------
// Phase 1: h = relu(A@W1+b1) via bf16 MFMA; fused epilogue -> D, W, emb parts
// 4096 blocks x 512 thr; BM=64, BN=512 (full), BK=32; 8 waves x (64r x 64c)
// A staged fp32->bf16 (trunc/v_perm) via LDS; B frags direct from L2 (W1T)
// __launch_bounds__(512,4): cap VGPR at 128 -> 2 blocks/CU
// ---------------------------------------------------------------------------
__global__ __launch_bounds__(512, 4) void fused_mlp(
    const float* __restrict__ A, const short* __restrict__ W1T,
    const float* __restrict__ b1, const float* __restrict__ W2,
    const float* __restrict__ b2, float* __restrict__ outD,
    float* __restrict__ outW, float* __restrict__ embpart)
{
    __shared__ short As[2][64 * 40];       // row stride 40 bf16 (80B)
    __shared__ float sp0[8][64], sp1[8][64];
    __shared__ float semb[8];

    const int tid = threadIdx.x;
    const int lane = tid & 63;
    const int wc = tid >> 6;               // wave id = column group 0..7
    const int l15 = lane & 15;
    const int l4 = lane >> 4;
    const int row0 = blockIdx.x * 64;

    f32x4 acc[4][4];
    #pragma unroll
    for (int m = 0; m < 4; m++)
        #pragma unroll
        for (int n = 0; n < 4; n++) {
            f32x4 z = {0.0f, 0.0f, 0.0f, 0.0f};
            acc[m][n] = z;
        }

    // A staging: thread -> row sr (0..63), k-chunk sk4 (4 consecutive k)
    const int sr = tid >> 3;
    const int sk4 = (tid & 7) * 4;
    const float* agp = A + (size_t)(row0 + sr) * HH + sk4;

    // prologue: stage k0=0 into buf 0
    {
        float4 a0 = *(const float4*)agp;
        unsigned w0 = pack_bf2(a0.x, a0.y);
        unsigned w1 = pack_bf2(a0.z, a0.w);
        uint2 w = {w0, w1};
        *(uint2*)&As[0][sr * 40 + sk4] = w;
    }
    __syncthreads();

    int cur = 0;
    #pragma unroll 1
    for (int s = 0; s < 16; s++) {
        const int k0 = s * 32;
        // B fragments direct from global (L2-resident W1T)
        bf16x8 bfr[4];
        #pragma unroll
        for (int n = 0; n < 4; n++) {
            int col = wc * 64 + n * 16 + l15;
            bfr[n] = *(const bf16x8*)(W1T + (size_t)col * HH + k0 + l4 * 8);
        }
        // prefetch next A chunk
        float4 pv;
        if (s < 15) pv = *(const float4*)(agp + k0 + 32);
        // A fragments from LDS
        bf16x8 af[4];
        #pragma unroll
        for (int m = 0; m < 4; m++)
            af[m] = *(const bf16x8*)&As[cur][(m * 16 + l15) * 40 + l4 * 8];
        #pragma unroll
        for (int m = 0; m < 4; m++)
            #pragma unroll
            for (int n = 0; n < 4; n++)
                acc[m][n] = __builtin_amdgcn_mfma_f32_16x16x32_bf16(
                    af[m], bfr[n], acc[m][n], 0, 0, 0);
        if (s < 15) {
            unsigned w0 = pack_bf2(pv.x, pv.y);
            unsigned w1 = pack_bf2(pv.z, pv.w);
            uint2 w = {w0, w1};
            *(uint2*)&As[cur ^ 1][sr * 40 + sk4] = w;
        }
        __syncthreads();
        cur ^= 1;
    }

    // epilogue: bias+relu, dot with W2 cols, emb partial
    float b1c[4], w20[4], w21[4];
    #pragma unroll
    for (int n = 0; n < 4; n++) {
        int col = wc * 64 + n * 16 + l15;
        b1c[n] = b1[col];
        w20[n] = W2[col * 2 + 0];
        w21[n] = W2[col * 2 + 1];
    }
    float embl = 0.0f;
    #pragma unroll
    for (int m = 0; m < 4; m++) {
        #pragma unroll
        for (int j = 0; j < 4; j++) {
            float s0 = 0.0f, s1 = 0.0f;
            #pragma unroll
            for (int n = 0; n < 4; n++) {
                float h = fmaxf(acc[m][n][j] + b1c[n], 0.0f);
                s0 = fmaf(h, w20[n], s0);
                s1 = fmaf(h, w21[n], s1);
                embl += h;
            }
            #pragma unroll
            for (int st = 1; st < 16; st <<= 1) {
                s0 += __shfl_xor(s0, st);
                s1 += __shfl_xor(s1, st);
            }
            if (l15 == 0) {
                int row = m * 16 + l4 * 4 + j;
                sp0[wc][row] = s0;
                sp1[wc][row] = s1;
            }
        }
    }
    #pragma unroll
    for (int st = 1; st < 64; st <<= 1) embl += __shfl_xor(embl, st);
    if (lane == 0) semb[wc] = embl;
    __syncthreads();
    if (tid < 64) {
        int gr = row0 + tid;
        float p0 = b2[0], p1 = b2[1];
        #pragma unroll
        for (int w = 0; w < 8; w++) { p0 += sp0[w][tid]; p1 += sp1[w][tid]; }
        int di = gr >> 9, dj = gr & 511;
        outD[gr] = (di == dj) ? 0.0f : softplus_f(p0);
        outW[gr] = softplus_f(p1);
    }
    if (tid == 0) {
        float e = 0.0f;
        #pragma unroll
        for (int w = 0; w < 8; w++) e += semb[w];
        embpart[blockIdx.x] = e;
    }
}

// ---------------------------------------------------------------------------
// single-stage all-to-all grid barrier: padded per-block flags, parallel poll
// ---------------------------------------------------------------------------
__device__ __forceinline__ void gbar(int* flags, int g)
{
    __syncthreads();
    if (threadIdx.x == 0)
        __hip_atomic_store(&flags[blockIdx.x * 16], g, __ATOMIC_RELEASE,
                           __HIP_MEMORY_SCOPE_AGENT);
    if (threadIdx.x < 32) {
        while (__hip_atomic_load(&flags[threadIdx.x * 16], __ATOMIC_ACQUIRE,
                                 __HIP_MEMORY_SCOPE_AGENT) < g)
            __builtin_amdgcn_s_sleep(2);
    }
    __syncthreads();
}

// ---------------------------------------------------------------------------
// Phases 2-4: 32 blocks x 256 threads, 16 rows/block
// ---------------------------------------------------------------------------
__global__ __launch_bounds__(256, 1) void coop_post(
    const float* __restrict__ Dg, const float* __restrict__ Wg,
    const float* __restrict__ noise, const float* __restrict__ uinit,
    float* __restrict__ outE, float* __restrict__ outX,
    float* __restrict__ ws)
{
    __shared__ float Dl[16][516];
    __shared__ float S1[16][520];
    __shared__ float S2[16][520];
    __shared__ float Xl[512][4];
    __shared__ float ul[512];
    __shared__ float upl[3][512];
    __shared__ float cm[512];          // column means (LDS-resident, redundant)
    __shared__ float rm[16];
    __shared__ float red4[4];

    const int tid = threadIdx.x;
    const int bid = blockIdx.x;
    const int r0 = bid * 16;

    float* embpart = ws + WS_EMB;
    float* colpart = ws + WS_COLP;
    float* ubuf0   = ws + WS_U0;
    float* ubuf1   = ws + WS_U1;
    float* Xg0     = ws + WS_X0;
    float* Xg1     = ws + WS_X1;
    int* flags     = (int*)(ws + WS_BAR);
    int bg = 0;

    // ---- phase 2a: load D rows, row means, column partial sums
    for (int idx = tid; idx < 16 * 512; idx += 256) {
        int r = idx >> 9, c = idx & 511;
        Dl[r][c] = Dg[(size_t)(r0 + r) * NN + c];
    }
    __syncthreads();
    {
        int r = tid >> 4, l = tid & 15;
        float s = 0.0f;
        for (int j = l; j < 512; j += 16) s += Dl[r][j];
        #pragma unroll
        for (int st = 1; st < 16; st <<= 1) s += __shfl_xor(s, st);
        if (l == 0) rm[r] = s * (1.0f / 512.0f);
    }
    for (int c = tid; c < 512; c += 256) {
        float s = 0.0f;
        #pragma unroll
        for (int r = 0; r < 16; r++) s += Dl[r][c];
        colpart[bid * 512 + c] = s;
    }
    gbar(flags, ++bg);

    // ---- phase 2b: column means redundantly into LDS; emb total (block 0)
    for (int c = tid; c < 512; c += 256) {
        float s = 0.0f;
        #pragma unroll
        for (int p = 0; p < 32; p++) s += colpart[p * 512 + c];
        cm[c] = s * (1.0f / 512.0f);
    }
    if (bid == 0) {
        float s = 0.0f;
        for (int i = tid; i < ROWS / 64; i += 256) s += embpart[i];
        s = block_sum(s, red4, tid);
        if (tid == 0) outE[0] = s;
    }
    __syncthreads();

    // ---- Dmean (redundant per block, from LDS cm)
    float Dmean;
    {
        float s = cm[tid] + cm[tid + 256];
        s = block_sum(s, red4, tid);
        Dmean = s * (1.0f / 512.0f);
    }

    // ---- phase 3: power iteration with implicit deflation
    const int mr = tid >> 4;
    const int ml = tid & 15;
    int cur = 0;
    #pragma unroll 1
    for (int rank = 0; rank < 3; rank++) {
        #pragma unroll 1
        for (int step = 0; step < 10; step++) {
            if (step == 0) {
                for (int t = tid; t < 512; t += 256) ul[t] = uinit[t * 3 + rank];
            } else {
                const float* ub = cur ? ubuf1 : ubuf0;
                for (int t = tid; t < 512; t += 256) ul[t] = ub[t];
            }
            __syncthreads();
            float vn = 0, vs = 0, vdr = 0, vd0 = 0, vd1 = 0;
            for (int t = tid; t < 512; t += 256) {
                float u = ul[t];
                vn = fmaf(u, u, vn);
                vs += u;
                vdr = fmaf(cm[t], u, vdr);
                if (rank > 0) vd0 = fmaf(upl[0][t], u, vd0);
                if (rank > 1) vd1 = fmaf(upl[1][t], u, vd1);
            }
            float nrm2 = block_sum(vn, red4, tid);
            float Su   = block_sum(vs, red4, tid);
            float dru  = block_sum(vdr, red4, tid);
            float d0u = 0, d1u = 0;
            if (rank > 0) d0u = block_sum(vd0, red4, tid);
            if (rank > 1) d1u = block_sum(vd1, red4, tid);
            float inv = 1.0f / fmaxf(sqrtf(nrm2), 0.001f);
            float S = Su * inv, dr = dru * inv;
            float d0s = d0u * inv, d1s = d1u * inv;
            float a = 0.0f;
            for (int j = ml; j < 512; j += 16) a = fmaf(Dl[mr][j], ul[j], a);
            #pragma unroll
            for (int st = 1; st < 16; st <<= 1) a += __shfl_xor(a, st);
            if (ml == 0) {
                float bvv = -0.5f * (a * inv - dr - rm[mr] * S + Dmean * S);
                if (rank > 0) bvv -= d0s * upl[0][r0 + mr];
                if (rank > 1) bvv -= d1s * upl[1][r0 + mr];
                float* ubn = cur ? ubuf0 : ubuf1;
                ubn[r0 + mr] = bvv;
            }
            gbar(flags, ++bg);
            cur ^= 1;
        }
        // finalize rank
        {
            const float* ub = cur ? ubuf1 : ubuf0;
            for (int t = tid; t < 512; t += 256) ul[t] = ub[t];
        }
        __syncthreads();
        float vn = 0.0f;
        for (int t = tid; t < 512; t += 256) { float u = ul[t]; vn = fmaf(u, u, vn); }
        float eig2 = block_sum(vn, red4, tid);
        float scl = sqrtf(sqrtf(eig2 + 0.01f));
        for (int t = tid; t < 512; t += 256) upl[rank][t] = ul[t] * scl;
        if (tid < 16) {
            int gr = r0 + tid;
            Xg0[gr * 4 + rank] = fmaf(ul[gr], scl, noise[gr * 3 + rank]);
            if (rank == 0) Xg0[gr * 4 + 3] = 0.0f;
        }
        __syncthreads();
    }

    // ---- phase 4 prep: SW = W+W^T, SWD = W.D + (W.D)^T (own rows)
    for (int idx = tid; idx < 16 * 512; idx += 256) {
        int r = idx >> 9, j = idx & 511;
        int gr = r0 + r;
        float wr = Wg[(size_t)gr * NN + j];
        float wc = Wg[(size_t)j * NN + gr];
        float dc = Dg[(size_t)j * NN + gr];
        S1[r][j] = wr + wc;
        S2[r][j] = fmaf(wr, Dl[r][j], wc * dc);
    }
    gbar(flags, ++bg);

    // ---- phase 4: 100 gradient-flow steps
    const int gr4 = (r0 + mr) * 4;
    int par = 0;
    #pragma unroll 1
    for (int t = 0; t < 100; t++) {
        const float* Xs = par ? Xg1 : Xg0;
        float* Xd = par ? Xg0 : Xg1;
        for (int i = tid; i < 512; i += 256)
            *reinterpret_cast<float4*>(&Xl[i][0]) =
                *reinterpret_cast<const float4*>(&Xs[i * 4]);
        __syncthreads();
        float xr0 = Xl[r0 + mr][0], xr1 = Xl[r0 + mr][1], xr2 = Xl[r0 + mr][2];
        float g0 = 0, g1 = 0, g2 = 0;
        for (int j = ml; j < 512; j += 16) {
            float dx0 = xr0 - Xl[j][0];
            float dx1 = xr1 - Xl[j][1];
            float dx2 = xr2 - Xl[j][2];
            float d2 = fmaf(dx0, dx0, fmaf(dx1, dx1, fmaf(dx2, dx2, 0.01f)));
            float ri = rsqrtf(d2);
            float coef = fmaf(S2[mr][j], ri, -S1[mr][j]);
            g0 = fmaf(coef, dx0, g0);
            g1 = fmaf(coef, dx1, g1);
            g2 = fmaf(coef, dx2, g2);
        }
        #pragma unroll
        for (int st = 1; st < 16; st <<= 1) {
            g0 += __shfl_xor(g0, st);
            g1 += __shfl_xor(g1, st);
            g2 += __shfl_xor(g2, st);
        }
        if (ml == 0) {
            float dX0 = 0.2f * g0, dX1 = 0.2f * g1, dX2 = 0.2f * g2;
            float sp = sqrtf(fmaf(dX0, dX0, fmaf(dX1, dX1, fmaf(dX2, dX2, 0.001f))));
            float alpha = 0.1f + 4.9f * (float)(100 - t) * 0.01f;
            float scal = alpha * tanhf(sp / alpha) / sp;
            Xd[gr4 + 0] = fmaf(dX0, scal, xr0);
            Xd[gr4 + 1] = fmaf(dX1, scal, xr1);
            Xd[gr4 + 2] = fmaf(dX2, scal, xr2);
        }
        gbar(flags, ++bg);
        par ^= 1;
    }
    if (tid < 16) {
        int gr = r0 + tid;
        const float* Xs = par ? Xg1 : Xg0;
        outX[gr * 3 + 0] = Xs[gr * 4 + 0];
        outX[gr * 3 + 1] = Xs[gr * 4 + 1];
        outX[gr * 3 + 2] = Xs[gr * 4 + 2];
    }
}

extern "C" void kernel_launch(void* const* d_in, const int* in_sizes, int n_in,
                              void* d_out, int out_size, void* d_ws, size_t ws_size,
                              hipStream_t stream)
{
    const float* A     = (const float*)d_in[0];
    const float* W1    = (const float*)d_in[1];
    const float* b1    = (const float*)d_in[2];
    const float* W2    = (const float*)d_in[3];
    const float* b2    = (const float*)d_in[4];
    const float* noise = (const float*)d_in[5];
    const float* uinit = (const float*)d_in[6];

    float* out  = (float*)d_out;
    float* outD = out;
    float* outW = out + ROWS;
    float* outE = out + 2 * ROWS;
    float* outX = out + 2 * ROWS + 1;
    float* ws   = (float*)d_ws;
    short* W1T  = (short*)(ws + WS_W1T);

    // reset barrier flags every call (graph replays reuse ws)
    hipMemsetAsync((char*)d_ws + (size_t)WS_BAR * sizeof(float), 0,
                   512 * sizeof(int), stream);

    hipLaunchKernelGGL(w1t_prep, dim3(256), dim3(256), 0, stream, W1, W1T);

    hipLaunchKernelGGL(fused_mlp, dim3(ROWS / 64), dim3(512), 0, stream,
                       A, W1T, b1, W2, b2, outD, outW, ws + WS_EMB);

    const float* Dg  = outD;
    const float* Wgc = outW;
    void* args[] = { (void*)&Dg, (void*)&Wgc, (void*)&noise, (void*)&uinit,
                     (void*)&outE, (void*)&outX, (void*)&ws };
    hipLaunchCooperativeKernel((const void*)coop_post, dim3(32), dim3(256),
                               args, 0, stream);
}